// Round 4
// baseline (257.273 us; speedup 1.0000x reference)
//
#include <hip/hip_runtime.h>

// Problem constants (fixed by setup_inputs): x is (1, 128, 128, 2048) fp32,
// channels-last. n=128 spatial, d=2048 channels.
constexpr int N_  = 128;
constexpr int D_  = 2048;
constexpr int NP_ = N_ * N_;      // 16384 spatial positions

// Native vector type: __builtin_nontemporal_load/store require scalar or
// native-vector pointers (HIP_vector_type float4 is rejected).
typedef float f32x4 __attribute__((ext_vector_type(4)));

// Monotone float->uint mapping: preserves total order of floats (incl. negatives).
// For any finite float, result >= 0x00800000 > 0, so zero-initialized keys are
// always beaten.
__device__ __forceinline__ unsigned int fmap(float f) {
    unsigned int b = __float_as_uint(f);
    return (b & 0x80000000u) ? ~b : (b | 0x80000000u);
}

// Pass 1: per-channel argmax via sortable 64-bit keys + atomicMax.
// key = (fmap(value) << 32) | (NP-1-p)  -> max key == max value, ties -> lowest p
// (matches jnp.argmax first-occurrence semantics).
// Grid: (2, 256). Each block: 256 threads x 4 channels (f32x4), 64 positions.
// 512 blocks -> 2 blocks/CU -> 2 waves/SIMD for latency hiding.
__global__ __launch_bounds__(256)
void argmax_kernel(const float* __restrict__ x,
                   unsigned long long* __restrict__ keys) {
    const int cIdx = blockIdx.x * 256 + threadIdx.x;   // f32x4 channel-group [0, 512)
    const int p0   = blockIdx.y * 64;
    const f32x4* __restrict__ x4 = (const f32x4*)x;

    unsigned long long b0 = 0, b1 = 0, b2 = 0, b3 = 0;
    #pragma unroll 8
    for (int p = p0; p < p0 + 64; ++p) {
        // lanes read consecutive f32x4 -> 1 KiB coalesced per wave load.
        // Regular (cached) load: this pass is what parks x in L3 for pass 2.
        f32x4 v = x4[(size_t)p * (D_ / 4) + cIdx];
        unsigned long long lo = (unsigned long long)(unsigned int)(NP_ - 1 - p);
        unsigned long long k0 = ((unsigned long long)fmap(v.x) << 32) | lo;
        unsigned long long k1 = ((unsigned long long)fmap(v.y) << 32) | lo;
        unsigned long long k2 = ((unsigned long long)fmap(v.z) << 32) | lo;
        unsigned long long k3 = ((unsigned long long)fmap(v.w) << 32) | lo;
        b0 = max(b0, k0);
        b1 = max(b1, k1);
        b2 = max(b2, k2);
        b3 = max(b3, k3);
    }
    unsigned long long* k = keys + (size_t)cIdx * 4;
    atomicMax(&k[0], b0);
    atomicMax(&k[1], b1);
    atomicMax(&k[2], b2);
    atomicMax(&k[3], b3);
}

// Pass 2: decode argmax per channel (16 KB key table -> L1-resident),
// compute mask, multiply. f32x4 in/out. x-read is the LAST use and the
// output is never re-read -> non-temporal on both to keep cache pressure low.
__global__ __launch_bounds__(256)
void apply_kernel(const float* __restrict__ x,
                  const unsigned long long* __restrict__ keys,
                  float* __restrict__ out) {
    const int g  = blockIdx.x * 256 + threadIdx.x;  // f32x4 index
    const int e  = g * 4;                           // element index
    const int c4 = e & (D_ - 1);                    // channel base (multiple of 4)
    const int p  = e >> 11;                         // spatial flat index = i*128 + j
    const float fi = (float)(p >> 7);               // row i
    const float fj = (float)(p & 127);              // col j

    f32x4 v = __builtin_nontemporal_load(((const f32x4*)x) + g);

    float m[4];
    #pragma unroll
    for (int t = 0; t < 4; ++t) {
        unsigned long long k = keys[c4 + t];
        unsigned int pm = (unsigned int)(NP_ - 1) - (unsigned int)(k & 0xFFFFFFFFull);
        // Reference's (deliberately transposed) decode: i_max = p % n, j_max = p / n
        float imax = (float)(pm & 127);
        float jmax = (float)(pm >> 7);
        float l1 = fabsf(fi - imax) + fabsf(fj - jmax);
        m[t] = fmaxf(-1.0f, 1.0f - l1 * (1.0f / 128.0f));
    }

    f32x4 o;
    o.x = v.x * m[0];
    o.y = v.y * m[1];
    o.z = v.z * m[2];
    o.w = v.w * m[3];
    __builtin_nontemporal_store(o, ((f32x4*)out) + g);
}

extern "C" void kernel_launch(void* const* d_in, const int* in_sizes, int n_in,
                              void* d_out, int out_size, void* d_ws, size_t ws_size,
                              hipStream_t stream) {
    const float* x = (const float*)d_in[0];
    float* out = (float*)d_out;
    unsigned long long* keys = (unsigned long long*)d_ws;

    // ws is re-poisoned to 0xAA before every timed launch -> must zero keys.
    // (capture-safe: becomes a memset node)
    (void)hipMemsetAsync(keys, 0, D_ * sizeof(unsigned long long), stream);

    dim3 g1(2, 256);
    argmax_kernel<<<g1, dim3(256), 0, stream>>>(x, keys);

    const int total4 = NP_ * D_ / 4;                 // 8,388,608 f32x4
    apply_kernel<<<total4 / 256, dim3(256), 0, stream>>>(x, keys, out);
}